// Round 12
// baseline (87.930 us; speedup 1.0000x reference)
//
#include <hip/hip_runtime.h>
#include <stdint.h>

typedef __attribute__((ext_vector_type(8))) short short8;      // 8 x bf16 (MFMA A/B frag)
typedef __attribute__((ext_vector_type(4))) float f32x4;       // MFMA acc frag
typedef __attribute__((ext_vector_type(4))) float f4;
typedef __attribute__((ext_vector_type(4))) unsigned short us4;

typedef unsigned short ushort_t;

__device__ __forceinline__ ushort_t f2bf(float f) {
    union { float f; uint32_t u; } c; c.f = f;
    uint32_t u = c.u;
    uint32_t r = u + 0x7fffu + ((u >> 16) & 1u);   // RNE
    return (ushort_t)(r >> 16);
}
__device__ __forceinline__ float bf2f(ushort_t h) {
    union { uint32_t u; float f; } c; c.u = ((uint32_t)h) << 16;
    return c.f;
}

// async global->LDS, 16B per lane; LDS dest = wave-uniform base + lane*16
typedef const __attribute__((address_space(1))) unsigned int as1_uint;
typedef __attribute__((address_space(3))) unsigned int as3_uint;
__device__ __forceinline__ void gload_lds16(const void* g, void* l) {
    __builtin_amdgcn_global_load_lds((as1_uint*)g, (as3_uint*)l, 16, 0, 0);
}

// LDS tile [R rows][64 cols] bf16, XOR-swizzled: element (r,c) lives at
// ushort index r*64 + (c ^ ((r&7)<<3)). LDS stays linear for global_load_lds;
// the inverse permutation is applied on the GLOBAL source chunk (rule #21).
#define SWIDX(r, c) ((r) * 64 + ((c) ^ (((r) & 7) << 3)))

// ---------------------------------------------------------------------------
// Weight prep: B^T ([N][K]) layouts.
// ---------------------------------------------------------------------------
__global__ void prep_weights(const float* __restrict__ gate_W, const float* __restrict__ B_W,
                             const float* __restrict__ C_W, const float* __restrict__ out_W,
                             ushort_t* __restrict__ W1t_hi, ushort_t* __restrict__ W1t_lo,
                             ushort_t* __restrict__ outWt, ushort_t* __restrict__ Ct)
{
    int idx = blockIdx.x * 256 + threadIdx.x;
    int stride = gridDim.x * 256;
    for (int i = idx; i < 1024 * 1024; i += stride) {
        int nn = i >> 10, kk = i & 1023;
        outWt[i] = f2bf(out_W[kk * 1024 + nn]);
    }
    for (int i = idx; i < 128 * 1024; i += stride) {
        int nn = i >> 10, kk = i & 1023;
        float v = (nn < 64) ? gate_W[kk * 64 + nn] : B_W[kk * 64 + (nn - 64)];
        ushort_t h = f2bf(v);
        W1t_hi[i] = h;
        W1t_lo[i] = f2bf(v - bf2f(h));
    }
    for (int i = idx; i < 1024 * 64; i += stride) {
        int nn = i >> 6, kk = i & 63;
        Ct[i] = f2bf(C_W[kk * 1024 + nn]);
    }
}

// ---------------------------------------------------------------------------
// P1: Z^T[n][s] = sum_k W1[k][n] * x[s][k], 2-PASS split precision.
// Split-K (2 chunks of 512). Writes x_hi (bf16 of x) as a staging byproduct.
// ---------------------------------------------------------------------------
__global__ __launch_bounds__(256, 2)
void p1_kernel(const float* __restrict__ x,
               const ushort_t* __restrict__ W1t_hi, const ushort_t* __restrict__ W1t_lo,
               ushort_t* __restrict__ x_hi, float* __restrict__ Zpart)
{
    __shared__ ushort_t Ash[128 * 64];
    __shared__ ushort_t Asl[128 * 64];
    __shared__ ushort_t Bsh[64 * 64];

    const int tid = threadIdx.x;
    const int wave = tid >> 6, lane = tid & 63;
    const int wm = wave >> 1, wn = wave & 1;
    const int s0 = blockIdx.x * 64;
    const int kc = blockIdx.y;

    f32x4 acc[4][2];
#pragma unroll
    for (int i = 0; i < 4; i++)
#pragma unroll
        for (int j = 0; j < 2; j++) { f32x4 z = {0.f,0.f,0.f,0.f}; acc[i][j] = z; }

    for (int kt = 0; kt < 8; ++kt) {
        const int k0 = kc * 512 + kt * 64;
#pragma unroll
        for (int p = 0; p < 4; ++p) {
            int c = p * 256 + wave * 64 + lane;
            int row = c >> 3, col = (c & 7) * 8;
            gload_lds16(W1t_hi + (size_t)row * 1024 + k0 + col,
                        &Ash[(p * 256 + wave * 64) * 8]);
            gload_lds16(W1t_lo + (size_t)row * 1024 + k0 + col,
                        &Asl[(p * 256 + wave * 64) * 8]);
        }
#pragma unroll
        for (int p = 0; p < 4; ++p) {
            int f = tid + p * 256;
            int row = f >> 4, col = (f & 15) * 4;
            f4 v = *(const f4*)(x + (size_t)(s0 + row) * 1024 + k0 + col);
            us4 hi;
#pragma unroll
            for (int j = 0; j < 4; j++) hi[j] = f2bf(v[j]);
            *(us4*)&Bsh[row * 64 + col] = hi;
            *(us4*)(x_hi + (size_t)(s0 + row) * 1024 + k0 + col) = hi;
        }
        __syncthreads();
#pragma unroll
        for (int kk = 0; kk < 2; ++kk) {
            const int kb = kk * 32 + (lane >> 4) * 8;
            short8 ah[4], al[4], bh[2];
#pragma unroll
            for (int fm = 0; fm < 4; fm++) {
                int r = wm * 64 + fm * 16 + (lane & 15);
                ah[fm] = *(const short8*)&Ash[r * 64 + kb];
                al[fm] = *(const short8*)&Asl[r * 64 + kb];
            }
#pragma unroll
            for (int fn = 0; fn < 2; fn++) {
                int r = wn * 32 + fn * 16 + (lane & 15);
                bh[fn] = *(const short8*)&Bsh[r * 64 + kb];
            }
#pragma unroll
            for (int fm = 0; fm < 4; fm++)
#pragma unroll
                for (int fn = 0; fn < 2; fn++) {
                    acc[fm][fn] = __builtin_amdgcn_mfma_f32_16x16x32_bf16(ah[fm], bh[fn], acc[fm][fn], 0, 0, 0);
                    acc[fm][fn] = __builtin_amdgcn_mfma_f32_16x16x32_bf16(al[fm], bh[fn], acc[fm][fn], 0, 0, 0);
                }
        }
        __syncthreads();
    }
#pragma unroll
    for (int fm = 0; fm < 4; fm++) {
#pragma unroll
        for (int fn = 0; fn < 2; fn++) {
            int scol = s0 + wn * 32 + fn * 16 + (lane & 15);
            int b = scol >> 12, sb = scol & 4095;
            int nbase = wm * 64 + fm * 16 + ((lane >> 4) << 2);
#pragma unroll
            for (int r = 0; r < 4; r++) {
                Zpart[((size_t)kc * 512 + b * 128 + nbase + r) * 4096 + sb] = acc[fm][fn][r];
            }
        }
    }
}

// ---------------------------------------------------------------------------
// Scan: combine split-K partials, gate = sigmoid(zg+bias), h_t = a_t*h + b_t.
// Output hT[b*64+n][s] bf16.
// ---------------------------------------------------------------------------
__global__ __launch_bounds__(256)
void scan_kernel(const float* __restrict__ Zpart, const float* __restrict__ gate_b,
                 ushort_t* __restrict__ hT)
{
    __shared__ float SA[256], SB[256];
    const int bn = blockIdx.x;
    const int t = threadIdx.x;
    const int b = bn >> 6, n = bn & 63;
    const float gb = gate_b[n];
    const float* g0 = Zpart + ((size_t)(b * 128 + n)) * 4096;
    const float* g1 = g0 + (size_t)512 * 4096;
    const float* b0 = Zpart + ((size_t)(b * 128 + 64 + n)) * 4096;
    const float* b1 = b0 + (size_t)512 * 4096;
    const int sb = t * 16;

    float a[16], bb[16];
#pragma unroll
    for (int q = 0; q < 4; q++) {
        f4 vg0 = *(const f4*)(g0 + sb + q * 4);
        f4 vg1 = *(const f4*)(g1 + sb + q * 4);
        f4 vb0 = *(const f4*)(b0 + sb + q * 4);
        f4 vb1 = *(const f4*)(b1 + sb + q * 4);
#pragma unroll
        for (int j = 0; j < 4; j++) {
            a[q * 4 + j] = 1.f / (1.f + __expf(-(vg0[j] + vg1[j] + gb)));
            bb[q * 4 + j] = vb0[j] + vb1[j];
        }
    }
    float A = 1.f, Bv = 0.f;
#pragma unroll
    for (int i = 0; i < 16; i++) { Bv = a[i] * Bv + bb[i]; A *= a[i]; }
    SA[t] = A; SB[t] = Bv;
    __syncthreads();
    for (int off = 1; off < 256; off <<= 1) {
        float a1 = 1.f, b1v = 0.f;
        if (t >= off) { a1 = SA[t - off]; b1v = SB[t - off]; }
        float a2 = SA[t], b2 = SB[t];
        __syncthreads();
        SA[t] = a1 * a2;
        SB[t] = a2 * b1v + b2;
        __syncthreads();
    }
    float h = (t == 0) ? 0.f : SB[t - 1];
    ushort_t ov[16];
#pragma unroll
    for (int i = 0; i < 16; i++) {
        h = a[i] * h + bb[i];
        ov[i] = f2bf(h);
    }
    ushort_t* dst = hT + (size_t)bn * 4096 + sb;
#pragma unroll
    for (int q = 0; q < 4; q++) {
        us4 o; o[0]=ov[q*4]; o[1]=ov[q*4+1]; o[2]=ov[q*4+2]; o[3]=ov[q*4+3];
        *(us4*)(dst + q * 4) = o;
    }
}

// ---------------------------------------------------------------------------
// gemm_out128: out = (h@C_W) * sigmoid(x_hi @ outWt^T).
// R12 = m97 TLP structure: 128x128 tile, 256 threads (4 waves 2x2, wave 64x64,
// 4x4 frags), SINGLE-buffer 32 KiB LDS, plain 2-barrier loop -> 3-4 blocks/CU
// co-resident; implicit wave-level overlap (m114) hides the per-tile vmcnt(0)
// drains. Carried-over proven fixes: T2 XOR-swizzle via pre-swizzled gload
// source (0 conflicts), conflict-free hT transpose, XCD chunk map, hoisted
// addressing, fused y epilogue. No setprio/sched_barrier (harmful in lockstep
// simple loops: m190/m141).
// ---------------------------------------------------------------------------
__global__ __launch_bounds__(256, 3)
void gemm_out128(const ushort_t* __restrict__ x_hi, const ushort_t* __restrict__ outWt,
                 const ushort_t* __restrict__ hT, const ushort_t* __restrict__ Ct,
                 float* __restrict__ out)
{
    __shared__ ushort_t As[128 * 64];   // 16 KiB
    __shared__ ushort_t Bs[128 * 64];   // 16 KiB

    const int tid = threadIdx.x;
    const int wave = tid >> 6, lane = tid & 63;
    const int wm = wave >> 1;          // 0..1 (m half: 64 rows)
    const int wn = wave & 1;           // 0..1 (n half: 64 cols)

    // XCD chunking: 1024 blocks; XCD k (= flat&7) owns m-tiles 16k..16k+15;
    // 16 consecutive locals share one n-panel (outWt 256KB stays L2-hot),
    // x_hi m-chunk (4 MB) re-read 8x from L2 across the n sweep.
    const int flat = blockIdx.x;
    const int xcd = flat & 7;
    const int local = flat >> 3;            // 0..127
    const int m0 = (xcd * 16 + (local & 15)) * 128;
    const int n0 = (local >> 4) * 128;

    const int lcol0 = (lane >> 4) * 8;
    const int lrow = lane & 15;
    const int lxor = (lrow & 7) << 3;

    // per-lane LDS read offsets (elements); fm/fn -> +1024 strides, kk -> ^32
    const int aOff0 = (wm * 64 + lrow) * 64 + (lcol0 ^ lxor);
    const int aOff1 = (wm * 64 + lrow) * 64 + ((32 + lcol0) ^ lxor);
    const int bOff0 = (wn * 64 + lrow) * 64 + (lcol0 ^ lxor);
    const int bOff1 = (wn * 64 + lrow) * 64 + ((32 + lcol0) ^ lxor);

    // persistent global stage streams: chunk c = tid + p*256; row = c>>3 =
    // (tid>>3) + p*32; col0 = ((tid&7) ^ ((tid>>3)&7))<<3  (p*32 % 8 == 0).
    const int rl0 = tid >> 3;                        // 0..31
    const int col0 = (((tid & 7) ^ (rl0 & 7)) << 3); // inverse-swizzled source
    const ushort_t* gA = x_hi + (size_t)(m0 + rl0) * 1024 + col0;
    const ushort_t* gB = outWt + (size_t)(n0 + rl0) * 1024 + col0;

    f32x4 acc[4][4];
#pragma unroll
    for (int i = 0; i < 4; i++)
#pragma unroll
        for (int j = 0; j < 4; j++) { f32x4 z = {0.f,0.f,0.f,0.f}; acc[i][j] = z; }

    for (int kt = 0; kt < 16; ++kt) {
        // stage tile kt (single buffer): 4 chunks A + 4 chunks B per thread
#pragma unroll
        for (int p = 0; p < 4; ++p) {
            gload_lds16(gA + (size_t)p * 32 * 1024, &As[p * 2048 + wave * 512]);
            gload_lds16(gB + (size_t)p * 32 * 1024, &Bs[p * 2048 + wave * 512]);
        }
        gA += 64; gB += 64;
        __syncthreads();   // compiler drains vmcnt before s_barrier (m97)

        short8 bfr[4][2];
#pragma unroll
        for (int fn = 0; fn < 4; ++fn) {
            bfr[fn][0] = *(const short8*)&As[0 /*dummy*/ + 0] ;  // placeholder removed below
        }
        // read B fragments
#pragma unroll
        for (int fn = 0; fn < 4; ++fn) {
            bfr[fn][0] = *(const short8*)&Bs[bOff0 + fn * 1024];
            bfr[fn][1] = *(const short8*)&Bs[bOff1 + fn * 1024];
        }
#pragma unroll
        for (int fm = 0; fm < 4; ++fm) {
            short8 a0 = *(const short8*)&As[aOff0 + fm * 1024];
            short8 a1 = *(const short8*)&As[aOff1 + fm * 1024];
#pragma unroll
            for (int fn = 0; fn < 4; ++fn) {
                acc[fm][fn] = __builtin_amdgcn_mfma_f32_16x16x32_bf16(a0, bfr[fn][0], acc[fm][fn], 0, 0, 0);
                acc[fm][fn] = __builtin_amdgcn_mfma_f32_16x16x32_bf16(a1, bfr[fn][1], acc[fm][fn], 0, 0, 0);
            }
        }
        __syncthreads();
    }

    // ---------- fused y epilogue: y = h @ C_W on this tile (K = 64) ----------
    const int b64 = (m0 >> 12) * 64;
    const int sb0 = m0 & 4095;
    // Bs <- Ct rows n0..n0+127 (gload_lds, pre-swizzled source)
#pragma unroll
    for (int p = 0; p < 4; ++p) {
        int c = tid + p * 256;
        int row = c >> 3;
        int col = (((c & 7) ^ (row & 7)) << 3);
        gload_lds16(Ct + (size_t)(n0 + row) * 64 + col,
                    &Bs[p * 2048 + wave * 512]);
    }
    // As <- transpose(hT). Conflict-free: kn = lane (per-lane consecutive),
    // mc = wave + p*4 (uniform). 64 lanes write one row, 64 consecutive
    // swizzled cols -> 2 lanes/bank = free. hT reads L2-resident.
#pragma unroll
    for (int p = 0; p < 4; ++p) {
        int c = tid + p * 256;           // kn = c&63 = lane, mc = c>>6
        int kn = c & 63, mc = c >> 6;    // mc 0..15
        short8 v = *(const short8*)(hT + (size_t)(b64 + kn) * 4096 + sb0 + mc * 8);
#pragma unroll
        for (int j = 0; j < 8; ++j)
            As[SWIDX(mc * 8 + j, kn)] = (ushort_t)v[j];
    }
    __syncthreads();

    short8 by[4][2];
#pragma unroll
    for (int fn = 0; fn < 4; fn++) {
        by[fn][0] = *(const short8*)&Bs[bOff0 + fn * 1024];
        by[fn][1] = *(const short8*)&Bs[bOff1 + fn * 1024];
    }

#pragma unroll
    for (int fm = 0; fm < 4; fm++) {     // register-sliced: 1 m-frag at a time
        f32x4 ty[4];
#pragma unroll
        for (int fn = 0; fn < 4; fn++) { f32x4 z = {0.f,0.f,0.f,0.f}; ty[fn] = z; }
        short8 a0 = *(const short8*)&As[aOff0 + fm * 1024];
        short8 a1 = *(const short8*)&As[aOff1 + fm * 1024];
#pragma unroll
        for (int fn = 0; fn < 4; fn++) {
            ty[fn] = __builtin_amdgcn_mfma_f32_16x16x32_bf16(a0, by[fn][0], ty[fn], 0, 0, 0);
            ty[fn] = __builtin_amdgcn_mfma_f32_16x16x32_bf16(a1, by[fn][1], ty[fn], 0, 0, 0);
        }
#pragma unroll
        for (int fn = 0; fn < 4; fn++) {
            int col = n0 + wn * 64 + fn * 16 + lrow;
            int rbase = m0 + wm * 64 + fm * 16 + ((lane >> 4) << 2);
#pragma unroll
            for (int r = 0; r < 4; r++) {
                float og = 1.f / (1.f + __expf(-acc[fm][fn][r]));
                out[(size_t)(rbase + r) * 1024 + col] = ty[fn][r] * og;
            }
        }
    }
}

// ---------------------------------------------------------------------------
extern "C" void kernel_launch(void* const* d_in, const int* in_sizes, int n_in,
                              void* d_out, int out_size, void* d_ws, size_t ws_size,
                              hipStream_t stream)
{
    const float* x      = (const float*)d_in[0];   // (4,4096,1024)
    const float* gate_W = (const float*)d_in[1];   // (1024,64)
    const float* gate_b = (const float*)d_in[2];   // (64,)
    const float* B_W    = (const float*)d_in[3];   // (1024,64)
    const float* C_W    = (const float*)d_in[4];   // (64,1024)
    const float* out_W  = (const float*)d_in[5];   // (1024,1024)
    // d_in[6] mix_weight cancels (h_next == h_final); d_in[7] chunk_size unused.
    float* out = (float*)d_out;

    char* ws = (char*)d_ws;
    float*    Zpart  = (float*)(ws + 0);            // 16 MiB [2][512][4096] fp32
    ushort_t* hT     = (ushort_t*)(ws + 16777216);  //  2 MiB [256][4096]
    ushort_t* x_hi   = (ushort_t*)(ws + 18874368);  // 32 MiB [16384][1024]
    ushort_t* W1t_hi = (ushort_t*)(ws + 52428800);  // [128][1024]
    ushort_t* W1t_lo = (ushort_t*)(ws + 52690944);
    ushort_t* outWt  = (ushort_t*)(ws + 52953088);  // [1024][1024]
    ushort_t* Ct     = (ushort_t*)(ws + 55050240);  // [1024][64]

    prep_weights<<<512, 256, 0, stream>>>(gate_W, B_W, C_W, out_W,
                                          W1t_hi, W1t_lo, outWt, Ct);

    p1_kernel<<<dim3(256, 2), 256, 0, stream>>>(x, W1t_hi, W1t_lo, x_hi, Zpart);

    scan_kernel<<<256, 256, 0, stream>>>(Zpart, gate_b, hT);

    gemm_out128<<<1024, 256, 0, stream>>>(x_hi, outWt, hT, Ct, out);
}